// Round 2
// baseline (6280.127 us; speedup 1.0000x reference)
//
#include <hip/hip_runtime.h>
#include <hip/hip_cooperative_groups.h>

namespace cg = cooperative_groups;

// Sizes (fixed): B=128, Tm1=64, M=P=512
typedef _Float16 v8h __attribute__((ext_vector_type(8)));
typedef _Float16 h2v __attribute__((ext_vector_type(2)));
typedef _Float16 h4v __attribute__((ext_vector_type(4)));
typedef float v4f __attribute__((ext_vector_type(4)));

__device__ __forceinline__ float fast_tanh(float x) {
    float e = __expf(2.0f * x);
    return 1.0f - 2.0f / (e + 1.0f);
}
__device__ __forceinline__ float fast_sigmoid(float x) {
    return 1.0f / (1.0f + __expf(-x));
}

// One persistent cooperative kernel: 256 blocks x 512 threads.
//  pre1: convert Xe,Wa1,Whh -> f16 ws copies; zero A=[d|c] (f16)
//  pre2: hx16 = f16(Xe @ Wa1[:,1024:]^T + ba1) via MFMA
//  loop t=0..63:
//    blocks [0,32):   s-GEMM tile (16 cols, K=1024, MFMA)    [blocks 32..160): glin
//    grid.sync()
//    blocks [192,256): pair p = bid-192: scores/softmax/context/ytilde/gates
//    grid.sync()
__global__ __launch_bounds__(512) void fused_decoder(
    const float* __restrict__ Xe, const float* __restrict__ ypr,
    const float* __restrict__ Wa1, const float* __restrict__ ba1,
    const float* __restrict__ Wa2, const float* __restrict__ ba2,
    const float* __restrict__ Wih, const float* __restrict__ Whh,
    const float* __restrict__ bih, const float* __restrict__ bhh,
    const float* __restrict__ Wfc, const float* __restrict__ bfc,
    const float* __restrict__ Wfin, const float* __restrict__ bfin,
    float* __restrict__ out,
    float* __restrict__ s, float* __restrict__ glin,
    _Float16* __restrict__ Xe16, _Float16* __restrict__ hx16,
    _Float16* __restrict__ Wa1a16, _Float16* __restrict__ Wa1x16,
    _Float16* __restrict__ Whh16, _Float16* __restrict__ Ab)
{
    cg::grid_group gg = cg::this_grid();
    const int bid = blockIdx.x;
    const int tid = threadIdx.x;
    const int wave = tid >> 6, lane = tid & 63;
    const int l15 = lane & 15, kq = lane >> 4;

    // Pair-block persistent LDS state
    __shared__ float cst[2][512];
    __shared__ float dst[2][512];
    __shared__ float ctxl[2][512];
    __shared__ float sc[128];
    __shared__ float ytl[2];
    __shared__ float red0;

    const int gt = bid * 512 + tid;   // grid-linear thread id, 131072 total

    // ---------------- pre-phase 1: f16 conversions ----------------
    {
        // Xe16: 4,194,304 f32 -> 1,048,576 float4 = 8 per thread
        const float4* Xe4 = (const float4*)Xe;
#pragma unroll
        for (int i = 0; i < 8; ++i) {
            size_t q = (size_t)gt * 8 + i;
            float4 v = Xe4[q];
            h4v h = { (_Float16)v.x, (_Float16)v.y, (_Float16)v.z, (_Float16)v.w };
            *(h4v*)(Xe16 + q * 4) = h;
        }
        // Wa1a16 [512][1024] from Wa1[e][0:1024): 131072 float4 = 1/thread
        {
            size_t q = gt;
            int row = (int)(q >> 8), c4 = (int)(q & 255);
            const float4 v = *(const float4*)(Wa1 + (size_t)row * 1536 + c4 * 4);
            h4v h = { (_Float16)v.x, (_Float16)v.y, (_Float16)v.z, (_Float16)v.w };
            *(h4v*)(Wa1a16 + (size_t)row * 1024 + c4 * 4) = h;
        }
        // Wa1x16 [512][512] from Wa1[e][1024:1536): 65536 float4 (half of threads)
        if (gt < 65536) {
            size_t q = gt;
            int row = (int)(q >> 7), c4 = (int)(q & 127);
            const float4 v = *(const float4*)(Wa1 + (size_t)row * 1536 + 1024 + c4 * 4);
            h4v h = { (_Float16)v.x, (_Float16)v.y, (_Float16)v.z, (_Float16)v.w };
            *(h4v*)(Wa1x16 + (size_t)row * 512 + c4 * 4) = h;
        }
        // Whh16 [2048][512]: 262144 float4 = 2/thread
#pragma unroll
        for (int i = 0; i < 2; ++i) {
            size_t q = (size_t)gt * 2 + i;
            const float4 v = *(const float4*)(Whh + q * 4);
            h4v h = { (_Float16)v.x, (_Float16)v.y, (_Float16)v.z, (_Float16)v.w };
            *(h4v*)(Whh16 + q * 4) = h;
        }
        // A=[d|c] zero: 131072 f16 = 1/thread
        Ab[gt] = (_Float16)0.0f;
        // pair-block LDS state zero
        for (int idx = tid; idx < 1024; idx += 512) {
            cst[idx >> 9][idx & 511] = 0.0f;
            dst[idx >> 9][idx & 511] = 0.0f;
        }
    }
    gg.sync();

    // ---------------- pre-phase 2: hx16 = f16(Xe@Wa1x^T + ba1) ----------------
    {
        // 16384 tiles (512 M x 32 N); per block 64 tiles; wave keeps M-tile fixed
        const int mt = bid * 2 + (wave >> 2);
        const _Float16* Abase = Xe16 + (size_t)(mt * 16 + l15) * 512 + kq * 8;
        v8h afr[16];
#pragma unroll
        for (int ks = 0; ks < 16; ++ks) afr[ks] = *(const v8h*)(Abase + ks * 32);
#pragma unroll
        for (int i = 0; i < 8; ++i) {
            const int nt = (wave & 3) * 8 + i;
            const _Float16* Bbase = Wa1x16 + (size_t)(nt * 16 + l15) * 512 + kq * 8;
            v4f acc = {};
#pragma unroll 4
            for (int ks = 0; ks < 16; ++ks)
                acc = __builtin_amdgcn_mfma_f32_16x16x32_f16(afr[ks], *(const v8h*)(Bbase + ks * 32), acc, 0, 0, 0);
            const float bav = ba1[nt * 16 + l15];
            _Float16* hrow = hx16 + (size_t)(mt * 16 + kq * 4) * 512 + nt * 16 + l15;
#pragma unroll
            for (int r = 0; r < 4; ++r) hrow[(size_t)r * 512] = (_Float16)(acc[r] + bav);
        }
    }
    gg.sync();

    // weight-col bias for glin blocks (static)
    float bb_g = 0.0f;
    if (bid >= 32 && bid < 160) {
        int col = (bid - 32) * 16 + l15;
        bb_g = bih[col] + bhh[col];
    }
    // pair-block static registers
    float w2v[8];
    float ba2v = 0.0f;
    const int p = bid - 192, b0 = 2 * p;
    if (bid >= 192) {
#pragma unroll
        for (int j = 0; j < 8; ++j) w2v[j] = Wa2[lane * 8 + j];
        ba2v = ba2[0];
    }

    // ---------------- main recurrence ----------------
    for (int t = 0; t < 64; ++t) {
        // ---- Phase G: s and glin GEMMs from Ab ----
        if (bid < 32) {                       // s tile: cols [16*bid, +16), K=1024
            const int col0 = bid * 16;
            const _Float16* Abase = Ab + (size_t)(wave * 16 + l15) * 1024 + kq * 8;
            const _Float16* Bbase = Wa1a16 + (size_t)(col0 + l15) * 1024 + kq * 8;
            v4f acc = {};
#pragma unroll 4
            for (int ks = 0; ks < 32; ++ks)
                acc = __builtin_amdgcn_mfma_f32_16x16x32_f16(
                    *(const v8h*)(Abase + ks * 32), *(const v8h*)(Bbase + ks * 32), acc, 0, 0, 0);
            float* srow = s + (size_t)(wave * 16 + kq * 4) * 512 + col0 + l15;
#pragma unroll
            for (int r = 0; r < 4; ++r) srow[(size_t)r * 512] = acc[r];
        } else if (bid < 160) {               // glin tile: cols [16*(bid-32), +16), K=512 (d only)
            const int col0 = (bid - 32) * 16;
            const _Float16* Abase = Ab + (size_t)(wave * 16 + l15) * 1024 + kq * 8;
            const _Float16* Bbase = Whh16 + (size_t)(col0 + l15) * 512 + kq * 8;
            v4f acc = {};
#pragma unroll 4
            for (int ks = 0; ks < 16; ++ks)
                acc = __builtin_amdgcn_mfma_f32_16x16x32_f16(
                    *(const v8h*)(Abase + ks * 32), *(const v8h*)(Bbase + ks * 32), acc, 0, 0, 0);
            float* grow = glin + (size_t)(wave * 16 + kq * 4) * 2048 + col0 + l15;
#pragma unroll
            for (int r = 0; r < 4; ++r) grow[(size_t)r * 2048] = acc[r] + bb_g;
        }
        gg.sync();

        // ---- Phase P: per batch-pair sequential chain ----
        if (bid >= 192) {
            // s rows for this pair into registers (lane owns e = lane*8..+8)
            float sreg[2][8];
#pragma unroll
            for (int blv = 0; blv < 2; ++blv) {
                const float4* sp = (const float4*)(s + (size_t)(b0 + blv) * 512 + lane * 8);
                float4 s0 = sp[0], s1 = sp[1];
                sreg[blv][0] = s0.x; sreg[blv][1] = s0.y; sreg[blv][2] = s0.z; sreg[blv][3] = s0.w;
                sreg[blv][4] = s1.x; sreg[blv][5] = s1.y; sreg[blv][6] = s1.z; sreg[blv][7] = s1.w;
            }
            // scores: 128 units (2b x 64t), 16 per wave
            for (int u0 = 0; u0 < 16; ++u0) {
                const int u = wave * 16 + u0;
                const int blv = u >> 6, tt = u & 63;
                const v8h hv = *(const v8h*)(hx16 + ((size_t)(b0 + blv) * 64 + tt) * 512 + lane * 8);
                float acc = 0.0f;
#pragma unroll
                for (int j = 0; j < 8; ++j) {
                    float x = sreg[blv][j] + (float)hv[j];
                    acc += w2v[j] * fast_tanh(x);
                }
#pragma unroll
                for (int off = 32; off; off >>= 1) acc += __shfl_xor(acc, off, 64);
                if (lane == 0) sc[u] = acc + ba2v;
            }
            __syncthreads();
            // joint softmax over the pair's 128 scores
            if (tid < 64) {
                float m2 = fmaxf(sc[tid], sc[tid + 64]);
#pragma unroll
                for (int off = 32; off; off >>= 1) m2 = fmaxf(m2, __shfl_xor(m2, off, 64));
                float e0v = __expf(sc[tid] - m2);
                float e1v = __expf(sc[tid + 64] - m2);
                sc[tid] = e0v; sc[tid + 64] = e1v;
                float ssum = e0v + e1v;
#pragma unroll
                for (int off = 32; off; off >>= 1) ssum += __shfl_xor(ssum, off, 64);
                if (tid == 0) red0 = 1.0f / ssum;
            }
            __syncthreads();
            const float inv = red0;
            // context: thread -> (bl, m-pair)
            {
                const int blv = tid >> 8, m2 = (tid & 255) * 2;
                const _Float16* xb = Xe16 + ((size_t)(b0 + blv) * 64) * 512 + m2;
                float a0 = 0.0f, a1 = 0.0f;
#pragma unroll 8
                for (int tt = 0; tt < 64; ++tt) {
                    h2v xv = *(const h2v*)(xb + (size_t)tt * 512);
                    float bta = sc[blv * 64 + tt];
                    a0 += bta * (float)xv[0];
                    a1 += bta * (float)xv[1];
                }
                ctxl[blv][m2] = a0 * inv;
                ctxl[blv][m2 + 1] = a1 * inv;
            }
            __syncthreads();
            // y_tilde
            if (tid < 128) {
                const int blv = tid >> 6, l2 = tid & 63;
                float acc = 0.0f;
#pragma unroll
                for (int j = 0; j < 8; ++j) {
                    int m = l2 * 8 + j;
                    acc += ctxl[blv][m] * Wfc[m];
                }
#pragma unroll
                for (int off = 32; off; off >>= 1) acc += __shfl_xor(acc, off, 64);
                if (l2 == 0)
                    ytl[blv] = acc + Wfc[512] * ypr[(size_t)(b0 + blv) * 64 + t] + bfc[0];
            }
            __syncthreads();
            // gates + state update; publish next A=[d|c] in f16
#pragma unroll
            for (int blv = 0; blv < 2; ++blv) {
                const int b = b0 + blv, pp = tid;
                const float* gl = glin + (size_t)b * 2048;
                const float yt = ytl[blv];
                float ii = gl[pp]         + yt * Wih[pp];
                float ff = gl[512 + pp]   + yt * Wih[512 + pp];
                float ggv = gl[1024 + pp] + yt * Wih[1024 + pp];
                float oo = gl[1536 + pp]  + yt * Wih[1536 + pp];
                float cprev = cst[blv][pp];
                float cn = fast_sigmoid(ff) * cprev + fast_sigmoid(ii) * fast_tanh(ggv);
                float dn = fast_sigmoid(oo) * fast_tanh(cn);
                cst[blv][pp] = cn;
                dst[blv][pp] = dn;
                Ab[(size_t)b * 1024 + pp]       = (_Float16)dn;
                Ab[(size_t)b * 1024 + 512 + pp] = (_Float16)cn;
            }
            if (t == 63) {
                __syncthreads();
                if (tid < 128) {
                    const int blv = tid >> 6, l2 = tid & 63;
                    float acc = 0.0f;
#pragma unroll
                    for (int j = 0; j < 8; ++j) {
                        int e = l2 * 8 + j;
                        acc += dst[blv][e] * Wfin[e] + ctxl[blv][e] * Wfin[512 + e];
                    }
#pragma unroll
                    for (int off = 32; off; off >>= 1) acc += __shfl_xor(acc, off, 64);
                    if (l2 == 0) out[b0 + blv] = acc + bfin[0];
                }
            }
        }
        gg.sync();
    }
}

extern "C" void kernel_launch(void* const* d_in, const int* in_sizes, int n_in,
                              void* d_out, int out_size, void* d_ws, size_t ws_size,
                              hipStream_t stream)
{
    const float* Xe   = (const float*)d_in[0];
    const float* ypr  = (const float*)d_in[1];
    const float* Wa1  = (const float*)d_in[2];
    const float* ba1  = (const float*)d_in[3];
    const float* Wa2  = (const float*)d_in[4];
    const float* ba2  = (const float*)d_in[5];
    const float* Wih  = (const float*)d_in[6];
    const float* Whh  = (const float*)d_in[7];
    const float* bih  = (const float*)d_in[8];
    const float* bhh  = (const float*)d_in[9];
    const float* Wfc  = (const float*)d_in[10];
    const float* bfc  = (const float*)d_in[11];
    const float* Wfin = (const float*)d_in[12];
    const float* bfin = (const float*)d_in[13];
    float* out = (float*)d_out;

    char* w = (char*)d_ws;
    float* s       = (float*)w;                     w += (size_t)128 * 512 * 4;     // 256 KB
    float* glin    = (float*)w;                     w += (size_t)128 * 2048 * 4;    // 1 MB
    _Float16* Xe16 = (_Float16*)w;                  w += (size_t)128 * 64 * 512 * 2; // 8 MB
    _Float16* hx16 = (_Float16*)w;                  w += (size_t)128 * 64 * 512 * 2; // 8 MB
    _Float16* Wa1a = (_Float16*)w;                  w += (size_t)512 * 1024 * 2;    // 1 MB
    _Float16* Wa1x = (_Float16*)w;                  w += (size_t)512 * 512 * 2;     // 0.5 MB
    _Float16* WhhH = (_Float16*)w;                  w += (size_t)2048 * 512 * 2;    // 2 MB
    _Float16* Ab   = (_Float16*)w;                  w += (size_t)128 * 1024 * 2;    // 256 KB

    void* args[] = {
        (void*)&Xe, (void*)&ypr, (void*)&Wa1, (void*)&ba1, (void*)&Wa2, (void*)&ba2,
        (void*)&Wih, (void*)&Whh, (void*)&bih, (void*)&bhh, (void*)&Wfc, (void*)&bfc,
        (void*)&Wfin, (void*)&bfin, (void*)&out,
        (void*)&s, (void*)&glin, (void*)&Xe16, (void*)&hx16,
        (void*)&Wa1a, (void*)&Wa1x, (void*)&WhhH, (void*)&Ab
    };
    hipLaunchCooperativeKernel((const void*)fused_decoder, dim3(256), dim3(512),
                               args, 0, stream);
}